// Round 5
// baseline (363.068 us; speedup 1.0000x reference)
//
#include <hip/hip_runtime.h>

// Problem constants (from reference)
#define NC 32768
#define ND 1024
#define NQ 256    // float4 chunks per row (ND/4)
#define NB 16384
#define KEEP 0.95f
#define OMK  0.05f   // 1 - keep
#define KCAP 16      // per-class sample-list cap; P(Poisson(0.5) >= 17) ~ 1e-19
#define RPG  4       // rows per group
#define NG   (NC / RPG)          // 8192 groups
#define GCAP 6       // prefetched gather entries per group (padded w=0); P(Poisson(2)>6)~0.45%
#define GMAX 64      // stored entries per group (hard cap)
#define ITERS 8      // groups per block
#define NBLK (NG / ITERS)        // 1024 blocks

typedef float fx4 __attribute__((ext_vector_type(4)));

// Kernel 1: count occurrences per class, scatter sample indices into
// per-class lists (order arbitrary; the index itself encodes batch order).
__global__ void count_scatter_kernel(const int* __restrict__ the_class,
                                     int* __restrict__ counts,
                                     int* __restrict__ idx_list) {
    int i = blockIdx.x * blockDim.x + threadIdx.x;
    if (i < NB) {
        int c = the_class[i];
        int pos = atomicAdd(&counts[c], 1);
        if (pos < KCAP) idx_list[c * KCAP + pos] = i;
    }
}

// Kernel 2: per-GROUP metadata. One thread per group of RPG=4 classes.
// decays[c] = keep^cnt. group_all[g][j] = {sample_idx | (row_in_group<<16),
// weight}; first max(n,GCAP) entries valid, entries [n,GCAP) padded {0,0}
// so the loss kernel can gather GCAP entries unconditionally.
__global__ void wprep_group_kernel(const int* __restrict__ counts,
                                   const int* __restrict__ idx_list,
                                   float* __restrict__ decays,
                                   int* __restrict__ group_n,
                                   int2* __restrict__ group_all) {
    int g = blockIdx.x * blockDim.x + threadIdx.x;
    if (g >= NG) return;
    int n = 0;
    for (int r = 0; r < RPG; ++r) {
        int c = g * RPG + r;
        int cnt = counts[c];
        float base = KEEP, dr = 1.0f;
        for (int e = cnt; e > 0; e >>= 1) { if (e & 1) dr *= base; base *= base; }
        decays[c] = dr;
        int m = cnt < KCAP ? cnt : KCAP;
        int idx[KCAP];
        for (int j = 0; j < m; ++j) idx[j] = idx_list[c * KCAP + j];
        for (int j = 0; j < m; ++j) {
            int later = 0;
            for (int l = 0; l < m; ++l) later += (idx[l] > idx[j]);
            float w = OMK;
            for (int k = 0; k < later; ++k) w *= KEEP;
            int2 e; e.x = idx[j] | (r << 16); e.y = __float_as_int(w);
            if (n < GMAX) group_all[(size_t)g * GMAX + n] = e;
            n++;
        }
    }
    int real = n < GMAX ? n : GMAX;
    for (int j = real; j < GCAP; ++j) {
        int2 e; e.x = 0; e.y = 0;
        group_all[(size_t)g * GMAX + j] = e;
    }
    group_n[g] = real;
}

// Kernel 3: fused EMA + L1 loss, software-pipelined. Block = 256 threads
// processes ITERS=8 groups of 4 rows; thread q owns float4 column q.
// Iteration i: issue group i+1's 14 wave-loads (4 s + 4 t + 6 gathers),
// consume group i, fetch group i+2's metadata. launch_bounds(256,2) gives
// the allocator 256 VGPRs so the double buffers stay in registers.
__global__ __launch_bounds__(256, 2) void loss_kernel(
    const float* __restrict__ s_logits,
    const float* __restrict__ t_logits,
    const float* __restrict__ logits,
    const float* __restrict__ decays,
    const int*   __restrict__ group_n,
    const int2*  __restrict__ group_all,
    float* __restrict__ out) {

    const int q  = threadIdx.x;          // float4 column 0..255
    const int g0 = blockIdx.x * ITERS;

    const fx4* s4 = (const fx4*)s_logits;
    const fx4* t4 = (const fx4*)t_logits;
    const fx4* l4 = (const fx4*)logits;
    const float4* dec4p = (const float4*)decays;   // RPG=4 decays per group

    float4 dec[2]; int gn[2]; int2 ent[2][GCAP];
    fx4 sv[2][RPG], tv[2][RPG], gv[2][GCAP];

    auto loadMeta = [&](int gi, int p) {
        dec[p] = dec4p[gi];
        gn[p]  = group_n[gi];
        #pragma unroll
        for (int j = 0; j < GCAP; ++j)
            ent[p][j] = group_all[(size_t)gi * GMAX + j];
    };
    auto issueData = [&](int gi, int p) {
        #pragma unroll
        for (int r = 0; r < RPG; ++r)
            sv[p][r] = s4[(gi * RPG + r) * NQ + q];
        #pragma unroll
        for (int r = 0; r < RPG; ++r)
            tv[p][r] = t4[(gi * RPG + r) * NQ + q];
        #pragma unroll
        for (int j = 0; j < GCAP; ++j)
            gv[p][j] = l4[(ent[p][j].x & 0xffff) * NQ + q];
    };

    float lsum = 0.0f;
    loadMeta(g0, 0);
    loadMeta(g0 + 1, 1);
    issueData(g0, 0);

    #pragma unroll
    for (int i = 0; i < ITERS; ++i) {
        const int p = i & 1;
        if (i + 1 < ITERS) issueData(g0 + i + 1, (i + 1) & 1);

        // ---- consume group i from buffer p ----
        fx4 acc[RPG];
        const float dd[RPG] = {dec[p].x, dec[p].y, dec[p].z, dec[p].w};
        #pragma unroll
        for (int r = 0; r < RPG; ++r) acc[r] = sv[p][r] * dd[r];

        #pragma unroll
        for (int j = 0; j < GCAP; ++j) {
            const int   rw = ent[p][j].x >> 16;
            const float w  = __int_as_float(ent[p][j].y);  // 0 for pad entries
            #pragma unroll
            for (int r = 0; r < RPG; ++r) {
                const float we = (rw == r) ? w : 0.0f;
                acc[r].x = fmaf(we, gv[p][j].x, acc[r].x);
                acc[r].y = fmaf(we, gv[p][j].y, acc[r].y);
                acc[r].z = fmaf(we, gv[p][j].z, acc[r].z);
                acc[r].w = fmaf(we, gv[p][j].w, acc[r].w);
            }
        }
        // Rare overflow tail (~0.45% of groups): entries beyond GCAP.
        const int n = gn[p];
        if (n > GCAP) {
            for (int j = GCAP; j < n; ++j) {
                int2 e = group_all[(size_t)(g0 + i) * GMAX + j];
                const int   rw = e.x >> 16;
                const float w  = __int_as_float(e.y);
                fx4 lv = l4[(e.x & 0xffff) * NQ + q];
                #pragma unroll
                for (int r = 0; r < RPG; ++r) {
                    const float we = (rw == r) ? w : 0.0f;
                    acc[r].x = fmaf(we, lv.x, acc[r].x);
                    acc[r].y = fmaf(we, lv.y, acc[r].y);
                    acc[r].z = fmaf(we, lv.z, acc[r].z);
                    acc[r].w = fmaf(we, lv.w, acc[r].w);
                }
            }
        }

        if (i + 2 < ITERS) loadMeta(g0 + i + 2, p);

        #pragma unroll
        for (int r = 0; r < RPG; ++r) {
            lsum += fabsf(acc[r].x - tv[p][r].x) + fabsf(acc[r].y - tv[p][r].y) +
                    fabsf(acc[r].z - tv[p][r].z) + fabsf(acc[r].w - tv[p][r].w);
        }
    }

    // Wave reduction (64 lanes) then cross-wave via LDS.
    #pragma unroll
    for (int off = 32; off > 0; off >>= 1) lsum += __shfl_down(lsum, off);
    __shared__ float wsum[4];
    const int wave = threadIdx.x >> 6, lane = threadIdx.x & 63;
    if (lane == 0) wsum[wave] = lsum;
    __syncthreads();
    if (threadIdx.x == 0) {
        float total = (wsum[0] + wsum[1] + wsum[2] + wsum[3]) * (1.0f / NC);
        atomicAdd(out, total);
    }
}

extern "C" void kernel_launch(void* const* d_in, const int* in_sizes, int n_in,
                              void* d_out, int out_size, void* d_ws, size_t ws_size,
                              hipStream_t stream) {
    const float* s_logits  = (const float*)d_in[0];
    const float* t_logits  = (const float*)d_in[1];
    const float* logits    = (const float*)d_in[2];
    const int*   the_class = (const int*)d_in[3];
    float* out = (float*)d_out;

    // workspace layout (~6.3 MB)
    int*   counts    = (int*)d_ws;                       // NC ints   (128 KB)
    int*   idx_list  = counts + NC;                      // NC*KCAP   (2 MB)
    float* decays    = (float*)(idx_list + NC * KCAP);   // NC floats (128 KB)
    int*   group_n   = (int*)(decays + NC);              // NG ints   (32 KB)
    int2*  group_all = (int2*)(group_n + NG);            // NG*GMAX int2 (4 MB)

    (void)hipMemsetAsync(counts, 0, NC * sizeof(int), stream);
    (void)hipMemsetAsync(d_out, 0, sizeof(float), stream);

    count_scatter_kernel<<<NB / 256, 256, 0, stream>>>(the_class, counts, idx_list);
    wprep_group_kernel<<<NG / 256, 256, 0, stream>>>(counts, idx_list, decays,
                                                     group_n, group_all);
    loss_kernel<<<NBLK, 256, 0, stream>>>(s_logits, t_logits, logits,
                                          decays, group_n, group_all, out);
}